// Round 1
// baseline (20.720 us; speedup 1.0000x reference)
//
#include <hip/hip_runtime.h>

// QuantumConv2D: x (64,1,256,256) f32, q_params (2,4) f32 -> out (64,1,128,128) f32.
// Per output pixel (b,i,j): patch v[4] = {x[2i][2j], x[2i][2j+1], x[2i+1][2j], x[2i+1][2j+1]}
// angles = tanh(v)*pi -> init product state; fixed weight circuit; measure <Z_3> (LSB).

__global__ void qc_prep(const float* __restrict__ qp, float* __restrict__ ws) {
    int i = threadIdx.x;
    if (i < 8) {
        float h = qp[i] * 0.5f;
        ws[2 * i]     = cosf(h);
        ws[2 * i + 1] = sinf(h);
    }
}

__global__ __launch_bounds__(256) void qc_main(const float* __restrict__ x,
                                               const float* __restrict__ wcs,
                                               float* __restrict__ out, int total) {
    int n = blockIdx.x * blockDim.x + threadIdx.x;
    if (n >= total) return;
    int j = n & 127;          // ow = 128
    int i = (n >> 7) & 127;   // oh = 128
    int b = n >> 14;          // batch
    const float* base = x + ((size_t)b << 16) + ((size_t)i << 9) + ((size_t)(j << 1));
    float2 r0 = *(const float2*)(base);
    float2 r1 = *(const float2*)(base + 256);
    float v[4] = {r0.x, r0.y, r1.x, r1.y};

    // encoding: theta = pi * tanh(v); c = cos(theta/2), s = sin(theta/2)
    // revolutions for v_sin/v_cos: (pi*t/2)/(2*pi) = t/4
    float c[4], s[4];
#pragma unroll
    for (int q = 0; q < 4; ++q) {
        float e = __expf(2.0f * v[q]);                       // e^{2v}
        float t = 1.0f - 2.0f * __builtin_amdgcn_rcpf(e + 1.0f);  // tanh(v), saturates correctly
        float rev = t * 0.25f;
        c[q] = __builtin_amdgcn_cosf(rev);
        s[q] = __builtin_amdgcn_sinf(rev);
    }

    // initial product state; wire q -> bit (3-q) of flat index (wire 0 = MSB)
    float psi[16];
#pragma unroll
    for (int i0 = 0; i0 < 2; ++i0)
#pragma unroll
        for (int i1 = 0; i1 < 2; ++i1)
#pragma unroll
            for (int i2 = 0; i2 < 2; ++i2)
#pragma unroll
                for (int i3 = 0; i3 < 2; ++i3)
                    psi[i0 * 8 + i1 * 4 + i2 * 2 + i3] =
                        (i0 ? s[0] : c[0]) * (i1 ? s[1] : c[1]) *
                        (i2 ? s[2] : c[2]) * (i3 ? s[3] : c[3]);

    // uniform weight cos/sin (precomputed by qc_prep)
    float cw[8], sw[8];
#pragma unroll
    for (int k = 0; k < 8; ++k) { cw[k] = wcs[2 * k]; sw[k] = wcs[2 * k + 1]; }

#pragma unroll
    for (int l = 0; l < 2; ++l) {
        // RY(weights[l][q]) on each wire
#pragma unroll
        for (int q = 0; q < 4; ++q) {
            const int m = 8 >> q;
            float C = cw[l * 4 + q], S = sw[l * 4 + q];
#pragma unroll
            for (int idx = 0; idx < 16; ++idx) {
                if (!(idx & m)) {
                    float a0 = psi[idx], a1 = psi[idx | m];
                    psi[idx]     = C * a0 - S * a1;
                    psi[idx | m] = S * a0 + C * a1;
                }
            }
        }
        // CNOT ring: (0->1),(1->2),(2->3),(3->0) — register permutation
#pragma unroll
        for (int q = 0; q < 4; ++q) {
            const int cb = 8 >> q;
            const int tb = 8 >> ((q + 1) & 3);
#pragma unroll
            for (int idx = 0; idx < 16; ++idx) {
                if ((idx & cb) && !(idx & tb)) {
                    float tmp = psi[idx];
                    psi[idx] = psi[idx | tb];
                    psi[idx | tb] = tmp;
                }
            }
        }
    }

    // <Z_{n-1}>: +|psi|^2 for LSB==0, - for LSB==1
    float acc = 0.0f;
#pragma unroll
    for (int idx = 0; idx < 16; ++idx) {
        float p2 = psi[idx] * psi[idx];
        acc += (idx & 1) ? -p2 : p2;
    }
    out[n] = acc;
}

extern "C" void kernel_launch(void* const* d_in, const int* in_sizes, int n_in,
                              void* d_out, int out_size, void* d_ws, size_t ws_size,
                              hipStream_t stream) {
    const float* x  = (const float*)d_in[0];
    const float* qp = (const float*)d_in[1];
    float* out = (float*)d_out;
    float* ws  = (float*)d_ws;

    qc_prep<<<1, 64, 0, stream>>>(qp, ws);
    int total = out_size;  // 64*128*128 = 1048576
    int blocks = (total + 255) / 256;
    qc_main<<<blocks, 256, 0, stream>>>(x, ws, out, total);
}

// Round 2
// 12.105 us; speedup vs baseline: 1.7117x; 1.7117x over previous
//
#include <hip/hip_runtime.h>

// QuantumConv2D fused: x (64,1,256,256) f32, q_params (2,4) f32 -> out (64,1,128,128) f32.
// Per output pixel: patch v[4], angles = pi*tanh(v); 4-qubit circuit:
//   encode RY(theta_q) + layer1 RY(w1_q)  == RY(theta_q + w1_q)  (merged, product state)
//   CNOT ring (register permutation)
//   layer2 RY(w2_q)
//   CNOT ring + measure <Z_3>  == sum_z (-1)^parity(z) chi(z)^2   (sign fold)
// One kernel, 2 pixels per thread, float4 loads / float2 stores.

__global__ __launch_bounds__(256) void qc_fused(const float* __restrict__ x,
                                                const float* __restrict__ qp,
                                                float* __restrict__ out,
                                                int totalPairs) {
    int n = blockIdx.x * blockDim.x + threadIdx.x;
    if (n >= totalPairs) return;          // 64*128*64 = 524288
    int j2 = n & 63;                      // pair-of-outputs index along row (64 per row)
    int i  = (n >> 6) & 127;              // output row
    int b  = n >> 13;                     // batch

    const float* base = x + ((size_t)b << 16) + ((size_t)i << 9) + ((size_t)j2 << 2);
    float4 r0 = *(const float4*)(base);        // input row 2i,   cols 4j2..4j2+3
    float4 r1 = *(const float4*)(base + 256);  // input row 2i+1

    // uniform weight constants (qp address is uniform -> scalar loads)
    const float inv4pi = 7.9577471545947674e-02f;  // 1/(4*pi)
    float w1rev[4], cw2[4], sw2[4];
#pragma unroll
    for (int q = 0; q < 4; ++q) {
        w1rev[q] = qp[q] * inv4pi;                 // layer-1 half-angle in revolutions
        float r2 = qp[4 + q] * inv4pi;             // layer-2 half-angle in revolutions
        cw2[q] = __builtin_amdgcn_cosf(r2);
        sw2[q] = __builtin_amdgcn_sinf(r2);
    }

    float res[2];
#pragma unroll
    for (int p = 0; p < 2; ++p) {
        float v[4];
        v[0] = p ? r0.z : r0.x;
        v[1] = p ? r0.w : r0.y;
        v[2] = p ? r1.z : r1.x;
        v[3] = p ? r1.w : r1.y;

        // merged encode+layer1 half-angle: rev = tanh(v)/4 + w1/(4pi)
        float c[4], s[4];
#pragma unroll
        for (int q = 0; q < 4; ++q) {
            float e = __expf(2.0f * v[q]);                        // e^{2v}
            float t = 1.0f - 2.0f * __builtin_amdgcn_rcpf(e + 1.0f);  // tanh(v)
            float rev = fmaf(t, 0.25f, w1rev[q]);
            c[q] = __builtin_amdgcn_cosf(rev);
            s[q] = __builtin_amdgcn_sinf(rev);
        }

        // product state psi0; wire q <-> bit (3-q) of flat index
        float p01[4] = { c[0] * c[1], c[0] * s[1], s[0] * c[1], s[0] * s[1] };
        float p23[4] = { c[2] * c[3], c[2] * s[3], s[2] * c[3], s[2] * s[3] };
        float psi[16];
#pragma unroll
        for (int a = 0; a < 4; ++a)
#pragma unroll
            for (int bb = 0; bb < 4; ++bb)
                psi[a * 4 + bb] = p01[a] * p23[bb];

        // first CNOT ring: pure basis permutation (compile-time register rename)
        float phi[16];
#pragma unroll
        for (int z = 0; z < 16; ++z) {
            int b0 = (z >> 3) & 1, b1 = (z >> 2) & 1, b2 = (z >> 1) & 1, b3 = z & 1;
            b1 ^= b0; b2 ^= b1; b3 ^= b2; b0 ^= b3;
            phi[(b0 << 3) | (b1 << 2) | (b2 << 1) | b3] = psi[z];
        }

        // layer-2 RYs
#pragma unroll
        for (int q = 0; q < 4; ++q) {
            const int m = 8 >> q;
            float C = cw2[q], S = sw2[q];
#pragma unroll
            for (int idx = 0; idx < 16; ++idx) {
                if (!(idx & m)) {
                    float a0 = phi[idx], a1 = phi[idx | m];
                    phi[idx]     = C * a0 - S * a1;
                    phi[idx | m] = S * a0 + C * a1;
                }
            }
        }

        // second ring + <Z_3>: sign = (-1)^{parity(z)}
        float pos = 0.0f, neg = 0.0f;
#pragma unroll
        for (int z = 0; z < 16; ++z) {
            int par = (z ^ (z >> 1) ^ (z >> 2) ^ (z >> 3)) & 1;
            if (par) neg = fmaf(phi[z], phi[z], neg);
            else     pos = fmaf(phi[z], phi[z], pos);
        }
        res[p] = pos - neg;
    }

    float2 o = make_float2(res[0], res[1]);
    *(float2*)(out + ((size_t)b << 14) + ((size_t)i << 7) + ((size_t)(j2 << 1))) = o;
}

extern "C" void kernel_launch(void* const* d_in, const int* in_sizes, int n_in,
                              void* d_out, int out_size, void* d_ws, size_t ws_size,
                              hipStream_t stream) {
    const float* x  = (const float*)d_in[0];
    const float* qp = (const float*)d_in[1];
    float* out = (float*)d_out;

    int totalPairs = out_size / 2;  // 524288
    int blocks = (totalPairs + 255) / 256;
    qc_fused<<<blocks, 256, 0, stream>>>(x, qp, out, totalPairs);
}

// Round 3
// 10.263 us; speedup vs baseline: 2.0190x; 1.1795x over previous
//
#include <hip/hip_runtime.h>

// QuantumConv2D, Pauli-collapsed closed form.
// x (64,1,256,256) f32, q_params (2,4) f32 -> out (64,1,128,128) f32.
// a_q = pi*tanh(v_q) + w0_q ;  C_q = cos a_q, S_q = sin a_q
// out = k1*C0C2 + k2*C1S2S3 + k3*C0S1S3 + k4*S0C1C2C3
//     + k5*C2S3 + k6*C0C1S2 + k7*S0S2C3 + k8*S1
// k's are fixed products of cos/sin(w1_q) (derived via Heisenberg conjugation
// of Z3 through ring -> RY(w1) -> ring; Y-containing strings vanish on the
// real product state).

__global__ __launch_bounds__(256) void qc_pauli(const float* __restrict__ x,
                                                const float* __restrict__ qp,
                                                float* __restrict__ out,
                                                int totalPairs) {
    int n = blockIdx.x * blockDim.x + threadIdx.x;
    if (n >= totalPairs) return;          // 64*128*64 = 524288
    int j2 = n & 63;                      // pair index along output row
    int i  = (n >> 6) & 127;              // output row
    int b  = n >> 13;                     // batch

    const float* base = x + ((size_t)b << 16) + ((size_t)i << 9) + ((size_t)j2 << 2);
    float4 r0 = *(const float4*)(base);        // input row 2i
    float4 r1 = *(const float4*)(base + 256);  // input row 2i+1

    const float inv2pi = 0.15915494309189535f;  // 1/(2*pi)

    // layer-0 weights: full-angle offsets in revolutions
    float w0rev[4];
#pragma unroll
    for (int q = 0; q < 4; ++q) w0rev[q] = qp[q] * inv2pi;

    // layer-1 weights -> the 8 Pauli coefficients (uniform across threads)
    float cw[4], sw[4];
#pragma unroll
    for (int q = 0; q < 4; ++q) {
        float r = qp[4 + q] * inv2pi;
        cw[q] = __builtin_amdgcn_cosf(r);
        sw[q] = __builtin_amdgcn_sinf(r);
    }
    float k1 =  cw[0] * cw[1] * cw[2] * cw[3];
    float k2 = -cw[0] * cw[1] * sw[2] * cw[3];
    float k3 =  cw[0] * sw[1] * sw[2] * cw[3];
    float k4 = -cw[0] * sw[1] * sw[2] * sw[3];
    float k5 =  sw[0] * cw[1] * cw[2] * sw[3];
    float k6 = -sw[0] * cw[1] * sw[2] * sw[3];
    float k7 =  sw[0] * sw[1] * cw[2] * cw[3];
    float k8 =  sw[0] * sw[1] * sw[2] * sw[3];

    float res[2];
#pragma unroll
    for (int p = 0; p < 2; ++p) {
        float v[4];
        v[0] = p ? r0.z : r0.x;
        v[1] = p ? r0.w : r0.y;
        v[2] = p ? r1.z : r1.x;
        v[3] = p ? r1.w : r1.y;

        float C[4], S[4];
#pragma unroll
        for (int q = 0; q < 4; ++q) {
            float e = __expf(2.0f * v[q]);                            // e^{2v}
            float t = 1.0f - 2.0f * __builtin_amdgcn_rcpf(e + 1.0f);  // tanh(v)
            float rev = fmaf(t, 0.5f, w0rev[q]);                      // a_q/(2pi)
            C[q] = __builtin_amdgcn_cosf(rev);
            S[q] = __builtin_amdgcn_sinf(rev);
        }

        float acc;
        acc = k8 * S[1];
        acc = fmaf(k1, C[0] * C[2], acc);
        acc = fmaf(k2, C[1] * (S[2] * S[3]), acc);
        acc = fmaf(k3, C[0] * (S[1] * S[3]), acc);
        acc = fmaf(k4, (S[0] * C[1]) * (C[2] * C[3]), acc);
        acc = fmaf(k5, C[2] * S[3], acc);
        acc = fmaf(k6, C[0] * (C[1] * S[2]), acc);
        acc = fmaf(k7, (S[0] * S[2]) * C[3], acc);
        res[p] = acc;
    }

    float2 o = make_float2(res[0], res[1]);
    *(float2*)(out + ((size_t)b << 14) + ((size_t)i << 7) + ((size_t)(j2 << 1))) = o;
}

extern "C" void kernel_launch(void* const* d_in, const int* in_sizes, int n_in,
                              void* d_out, int out_size, void* d_ws, size_t ws_size,
                              hipStream_t stream) {
    const float* x  = (const float*)d_in[0];
    const float* qp = (const float*)d_in[1];
    float* out = (float*)d_out;

    int totalPairs = out_size / 2;  // 524288
    int blocks = (totalPairs + 255) / 256;
    qc_pauli<<<blocks, 256, 0, stream>>>(x, qp, out, totalPairs);
}

// Round 4
// 10.047 us; speedup vs baseline: 2.0624x; 1.0215x over previous
//
#include <hip/hip_runtime.h>

// QuantumConv2D, Pauli-collapsed closed form, 4 pixels/thread.
// x (64,1,256,256) f32, q_params (2,4) f32 -> out (64,1,128,128) f32.
// a_q = pi*tanh(v_q) + w0_q ;  C_q = cos a_q, S_q = sin a_q
// out = k1*C0C2 + k2*C1S2S3 + k3*C0S1S3 + k4*S0C1C2C3
//     + k5*C2S3 + k6*C0C1S2 + k7*S0S2C3 + k8*S1
// (Heisenberg conjugation of Z3 through ring -> RY(w1) -> ring; Y-strings
// vanish on the real product state; encode-RY and layer-0 RY merged.)

__global__ __launch_bounds__(256) void qc_pauli4(const float* __restrict__ x,
                                                 const float* __restrict__ qp,
                                                 float* __restrict__ out,
                                                 int totalQuads) {
    int n = blockIdx.x * blockDim.x + threadIdx.x;
    if (n >= totalQuads) return;          // 64*128*32 = 262144
    int j4 = n & 31;                      // quad index along output row (32 per row)
    int i  = (n >> 5) & 127;              // output row
    int b  = n >> 12;                     // batch

    const float* base = x + ((size_t)b << 16) + ((size_t)i << 9) + ((size_t)j4 << 3);
    float4 r0a = *(const float4*)(base);        // row 2i,   cols 8j4..+3
    float4 r0b = *(const float4*)(base + 4);    // row 2i,   cols +4..+7
    float4 r1a = *(const float4*)(base + 256);  // row 2i+1
    float4 r1b = *(const float4*)(base + 260);
    float row0[8] = {r0a.x, r0a.y, r0a.z, r0a.w, r0b.x, r0b.y, r0b.z, r0b.w};
    float row1[8] = {r1a.x, r1a.y, r1a.z, r1a.w, r1b.x, r1b.y, r1b.z, r1b.w};

    const float inv2pi = 0.15915494309189535f;  // 1/(2*pi)

    // layer-0 weights: full-angle offsets in revolutions (uniform, scalar loads)
    float w0rev[4];
#pragma unroll
    for (int q = 0; q < 4; ++q) w0rev[q] = qp[q] * inv2pi;

    // layer-1 weights -> 8 Pauli coefficients (uniform)
    float cw[4], sw[4];
#pragma unroll
    for (int q = 0; q < 4; ++q) {
        float r = qp[4 + q] * inv2pi;
        cw[q] = __builtin_amdgcn_cosf(r);
        sw[q] = __builtin_amdgcn_sinf(r);
    }
    float k1 =  cw[0] * cw[1] * cw[2] * cw[3];
    float k2 = -cw[0] * cw[1] * sw[2] * cw[3];
    float k3 =  cw[0] * sw[1] * sw[2] * cw[3];
    float k4 = -cw[0] * sw[1] * sw[2] * sw[3];
    float k5 =  sw[0] * cw[1] * cw[2] * sw[3];
    float k6 = -sw[0] * cw[1] * sw[2] * sw[3];
    float k7 =  sw[0] * sw[1] * cw[2] * cw[3];
    float k8 =  sw[0] * sw[1] * sw[2] * sw[3];

    float res[4];
#pragma unroll
    for (int p = 0; p < 4; ++p) {
        float v[4] = { row0[2 * p], row0[2 * p + 1], row1[2 * p], row1[2 * p + 1] };

        float C[4], S[4];
#pragma unroll
        for (int q = 0; q < 4; ++q) {
            float e = __expf(2.0f * v[q]);                            // e^{2v}
            float t = 1.0f - 2.0f * __builtin_amdgcn_rcpf(e + 1.0f);  // tanh(v)
            float rev = fmaf(t, 0.5f, w0rev[q]);                      // a_q/(2pi)
            C[q] = __builtin_amdgcn_cosf(rev);
            S[q] = __builtin_amdgcn_sinf(rev);
        }

        float acc;
        acc = k8 * S[1];
        acc = fmaf(k1, C[0] * C[2], acc);
        acc = fmaf(k2, C[1] * (S[2] * S[3]), acc);
        acc = fmaf(k3, C[0] * (S[1] * S[3]), acc);
        acc = fmaf(k4, (S[0] * C[1]) * (C[2] * C[3]), acc);
        acc = fmaf(k5, C[2] * S[3], acc);
        acc = fmaf(k6, C[0] * (C[1] * S[2]), acc);
        acc = fmaf(k7, (S[0] * S[2]) * C[3], acc);
        res[p] = acc;
    }

    float4 o = make_float4(res[0], res[1], res[2], res[3]);
    *(float4*)(out + ((size_t)b << 14) + ((size_t)i << 7) + ((size_t)(j4 << 2))) = o;
}

extern "C" void kernel_launch(void* const* d_in, const int* in_sizes, int n_in,
                              void* d_out, int out_size, void* d_ws, size_t ws_size,
                              hipStream_t stream) {
    const float* x  = (const float*)d_in[0];
    const float* qp = (const float*)d_in[1];
    float* out = (float*)d_out;

    int totalQuads = out_size / 4;  // 262144
    int blocks = (totalQuads + 255) / 256;
    qc_pauli4<<<blocks, 256, 0, stream>>>(x, qp, out, totalQuads);
}